// Round 1
// baseline (1221.744 us; speedup 1.0000x reference)
//
#include <hip/hip_runtime.h>
#include <math.h>

#define NN 50000
#define EE 800000
#define TOT (EE + NN)          // 850000 edges incl. self loops
#define CC 128
#define HH 4
#define HCW 512                // H*C

// ---- monotone float<->uint mapping for atomicMax on signed floats ----
__device__ __forceinline__ unsigned f2mono(float f) {
    unsigned u = __float_as_uint(f);
    return (u & 0x80000000u) ? ~u : (u | 0x80000000u);
}
__device__ __forceinline__ float mono2f(unsigned m) {
    return (m & 0x80000000u) ? __uint_as_float(m ^ 0x80000000u)
                             : __uint_as_float(~m);
}

// ---------------- K1: xh = x @ W, fused a_src/a_dst ----------------
// block = 256 threads (4 waves). 32 rows per block, 8 rows per wave.
// lane owns 8 consecutive output cols c0 = lane*8 (all within one head).
__global__ __launch_bounds__(256) void k_gemm(
    const float* __restrict__ x, const float* __restrict__ W,
    const float* __restrict__ att_s, const float* __restrict__ att_d,
    float* __restrict__ xh, float* __restrict__ asrc, float* __restrict__ adst)
{
    __shared__ float xs[32][CC];
    const int tid = threadIdx.x;
    const int block_row0 = blockIdx.x * 32;

    // stage 32 x-rows (float4 loads)
    for (int i = tid; i < 32 * 32; i += 256) {
        int r  = i >> 5;        // local row
        int c4 = i & 31;        // float4 index within row
        int row = block_row0 + r;
        float4 v;
        if (row < NN) v = *(const float4*)(x + (size_t)row * CC + c4 * 4);
        else          v = make_float4(0.f, 0.f, 0.f, 0.f);
        *(float4*)(&xs[r][c4 * 4]) = v;
    }
    __syncthreads();

    const int wv   = tid >> 6;
    const int lane = tid & 63;
    const int r0   = wv * 8;               // local row base for this wave
    const int row0 = block_row0 + r0;
    const int c0   = lane * 8;             // output col base (0..504)
    const int h    = c0 >> 7;              // head index
    const int hc0  = c0 & 127;

    const float4 s0 = *(const float4*)(att_s + h * CC + hc0);
    const float4 s1 = *(const float4*)(att_s + h * CC + hc0 + 4);
    const float4 d0 = *(const float4*)(att_d + h * CC + hc0);
    const float4 d1 = *(const float4*)(att_d + h * CC + hc0 + 4);

    float acc[8][8];
#pragma unroll
    for (int r = 0; r < 8; ++r)
#pragma unroll
        for (int j = 0; j < 8; ++j) acc[r][j] = 0.f;

#pragma unroll 4
    for (int k = 0; k < CC; ++k) {
        const float4 w0 = *(const float4*)(W + (size_t)k * HCW + c0);
        const float4 w1 = *(const float4*)(W + (size_t)k * HCW + c0 + 4);
#pragma unroll
        for (int r = 0; r < 8; ++r) {
            const float xv = xs[r0 + r][k];   // wave-uniform broadcast read
            acc[r][0] += xv * w0.x; acc[r][1] += xv * w0.y;
            acc[r][2] += xv * w0.z; acc[r][3] += xv * w0.w;
            acc[r][4] += xv * w1.x; acc[r][5] += xv * w1.y;
            acc[r][6] += xv * w1.z; acc[r][7] += xv * w1.w;
        }
    }

#pragma unroll
    for (int r = 0; r < 8; ++r) {
        const int row = row0 + r;
        if (row >= NN) continue;
        float4 o0 = make_float4(acc[r][0], acc[r][1], acc[r][2], acc[r][3]);
        float4 o1 = make_float4(acc[r][4], acc[r][5], acc[r][6], acc[r][7]);
        *(float4*)(xh + (size_t)row * HCW + c0)     = o0;
        *(float4*)(xh + (size_t)row * HCW + c0 + 4) = o1;

        float ps = acc[r][0]*s0.x + acc[r][1]*s0.y + acc[r][2]*s0.z + acc[r][3]*s0.w
                 + acc[r][4]*s1.x + acc[r][5]*s1.y + acc[r][6]*s1.z + acc[r][7]*s1.w;
        float pd = acc[r][0]*d0.x + acc[r][1]*d0.y + acc[r][2]*d0.z + acc[r][3]*d0.w
                 + acc[r][4]*d1.x + acc[r][5]*d1.y + acc[r][6]*d1.z + acc[r][7]*d1.w;
        // reduce across the 16 lanes of this head group
#pragma unroll
        for (int off = 1; off < 16; off <<= 1) {
            ps += __shfl_xor(ps, off);
            pd += __shfl_xor(pd, off);
        }
        if ((lane & 15) == 0) {
            asrc[row * HH + h] = ps;
            adst[row * HH + h] = pd;
        }
    }
}

// -------- K2: raw scores + segment max (atomicMax on mono uint) --------
__global__ __launch_bounds__(256) void k_edge_max(
    const int* __restrict__ ei, const float* __restrict__ asrc,
    const float* __restrict__ adst, unsigned* __restrict__ mm)
{
    const int e = blockIdx.x * 256 + threadIdx.x;
    if (e >= TOT) return;
    int s, d;
    if (e < EE) { s = ei[e]; d = ei[EE + e]; } else { s = d = e - EE; }
    const float4 a = *(const float4*)(asrc + (size_t)s * HH);
    const float4 b = *(const float4*)(adst + (size_t)d * HH);
    float v0 = a.x + b.x; v0 = v0 > 0.f ? v0 : 0.2f * v0;
    float v1 = a.y + b.y; v1 = v1 > 0.f ? v1 : 0.2f * v1;
    float v2 = a.z + b.z; v2 = v2 > 0.f ? v2 : 0.2f * v2;
    float v3 = a.w + b.w; v3 = v3 > 0.f ? v3 : 0.2f * v3;
    atomicMax(mm + (size_t)d * HH + 0, f2mono(v0));
    atomicMax(mm + (size_t)d * HH + 1, f2mono(v1));
    atomicMax(mm + (size_t)d * HH + 2, f2mono(v2));
    atomicMax(mm + (size_t)d * HH + 3, f2mono(v3));
}

// -------- K3: p = exp(e - m), segment sum --------
__global__ __launch_bounds__(256) void k_edge_sum(
    const int* __restrict__ ei, const float* __restrict__ asrc,
    const float* __restrict__ adst, const unsigned* __restrict__ mm,
    float* __restrict__ ss)
{
    const int e = blockIdx.x * 256 + threadIdx.x;
    if (e >= TOT) return;
    int s, d;
    if (e < EE) { s = ei[e]; d = ei[EE + e]; } else { s = d = e - EE; }
    const float4 a = *(const float4*)(asrc + (size_t)s * HH);
    const float4 b = *(const float4*)(adst + (size_t)d * HH);
    const uint4  m4 = *(const uint4*)(mm + (size_t)d * HH);
    float v0 = a.x + b.x; v0 = v0 > 0.f ? v0 : 0.2f * v0;
    float v1 = a.y + b.y; v1 = v1 > 0.f ? v1 : 0.2f * v1;
    float v2 = a.z + b.z; v2 = v2 > 0.f ? v2 : 0.2f * v2;
    float v3 = a.w + b.w; v3 = v3 > 0.f ? v3 : 0.2f * v3;
    atomicAdd(ss + (size_t)d * HH + 0, expf(v0 - mono2f(m4.x)));
    atomicAdd(ss + (size_t)d * HH + 1, expf(v1 - mono2f(m4.y)));
    atomicAdd(ss + (size_t)d * HH + 2, expf(v2 - mono2f(m4.z)));
    atomicAdd(ss + (size_t)d * HH + 3, expf(v3 - mono2f(m4.w)));
}

// -------- K4: weighted scatter-add, one wave per edge --------
// lane owns 2 channels; accumulate Sum_h (w_h/H) * xh[src][h][c] -> refined[dst][c]
__global__ __launch_bounds__(256) void k_aggr(
    const int* __restrict__ ei, const float* __restrict__ asrc,
    const float* __restrict__ adst, const unsigned* __restrict__ mm,
    const float* __restrict__ ss, const float* __restrict__ xh,
    float* __restrict__ refined)
{
    const int gtid = blockIdx.x * 256 + threadIdx.x;
    const int wid  = gtid >> 6;
    const int lane = threadIdx.x & 63;
    if (wid >= TOT) return;
    int s, d;
    if (wid < EE) { s = ei[wid]; d = ei[EE + wid]; } else { s = d = wid - EE; }

    const float4 a  = *(const float4*)(asrc + (size_t)s * HH);
    const float4 b  = *(const float4*)(adst + (size_t)d * HH);
    const uint4  m4 = *(const uint4*)(mm + (size_t)d * HH);
    const float4 s4 = *(const float4*)(ss + (size_t)d * HH);

    float w[4];
    {
        float v;
        v = a.x + b.x; v = v > 0.f ? v : 0.2f * v;
        w[0] = expf(v - mono2f(m4.x)) / (s4.x + 1e-16f) * 0.25f;
        v = a.y + b.y; v = v > 0.f ? v : 0.2f * v;
        w[1] = expf(v - mono2f(m4.y)) / (s4.y + 1e-16f) * 0.25f;
        v = a.z + b.z; v = v > 0.f ? v : 0.2f * v;
        w[2] = expf(v - mono2f(m4.z)) / (s4.z + 1e-16f) * 0.25f;
        v = a.w + b.w; v = v > 0.f ? v : 0.2f * v;
        w[3] = expf(v - mono2f(m4.w)) / (s4.w + 1e-16f) * 0.25f;
    }

    const int c = lane * 2;
    const float* xr = xh + (size_t)s * HCW + c;
    const float2 x0 = *(const float2*)(xr);
    const float2 x1 = *(const float2*)(xr + CC);
    const float2 x2 = *(const float2*)(xr + 2 * CC);
    const float2 x3 = *(const float2*)(xr + 3 * CC);
    const float r0 = w[0]*x0.x + w[1]*x1.x + w[2]*x2.x + w[3]*x3.x;
    const float r1 = w[0]*x0.y + w[1]*x1.y + w[2]*x2.y + w[3]*x3.y;
    atomicAdd(refined + (size_t)d * CC + c,     r0);
    atomicAdd(refined + (size_t)d * CC + c + 1, r1);
}

// -------- K5: out = 0.8*x + 0.2*(refined + bias) --------
__global__ __launch_bounds__(256) void k_final(
    const float* __restrict__ x, const float* __restrict__ refined,
    const float* __restrict__ bias, float* __restrict__ out)
{
    const int i = blockIdx.x * 256 + threadIdx.x;   // float4 index
    if (i >= NN * (CC / 4)) return;
    const int n  = i >> 5;
    const int c4 = (i & 31) * 4;
    const float4 xv = *(const float4*)(x + (size_t)n * CC + c4);
    const float4 rv = *(const float4*)(refined + (size_t)n * CC + c4);
    const float4 bv = *(const float4*)(bias + c4);
    float4 o;
    o.x = 0.8f * xv.x + 0.2f * (rv.x + bv.x);
    o.y = 0.8f * xv.y + 0.2f * (rv.y + bv.y);
    o.z = 0.8f * xv.z + 0.2f * (rv.z + bv.z);
    o.w = 0.8f * xv.w + 0.2f * (rv.w + bv.w);
    *(float4*)(out + (size_t)n * CC + c4) = o;
}

extern "C" void kernel_launch(void* const* d_in, const int* in_sizes, int n_in,
                              void* d_out, int out_size, void* d_ws, size_t ws_size,
                              hipStream_t stream)
{
    const float* x     = (const float*)d_in[0];
    const int*   ei    = (const int*)d_in[1];
    const float* W     = (const float*)d_in[2];
    const float* att_s = (const float*)d_in[3];
    const float* att_d = (const float*)d_in[4];
    const float* bias  = (const float*)d_in[5];
    float* out = (float*)d_out;

    float* ws = (float*)d_ws;
    float*    xh      = ws;                                   // N*512
    float*    asrc    = xh + (size_t)NN * HCW;                // N*4
    float*    adst    = asrc + (size_t)NN * HH;               // N*4
    unsigned* mm      = (unsigned*)(adst + (size_t)NN * HH);  // N*4
    float*    ss      = (float*)(mm + (size_t)NN * HH);       // N*4
    float*    refined = ss + (size_t)NN * HH;                 // N*128

    // zero the accumulators (mm, ss, refined are contiguous)
    hipMemsetAsync(mm, 0, ((size_t)NN * HH * 2 + (size_t)NN * CC) * sizeof(float), stream);

    k_gemm<<<(NN + 31) / 32, 256, 0, stream>>>(x, W, att_s, att_d, xh, asrc, adst);
    k_edge_max<<<(TOT + 255) / 256, 256, 0, stream>>>(ei, asrc, adst, mm);
    k_edge_sum<<<(TOT + 255) / 256, 256, 0, stream>>>(ei, asrc, adst, mm, ss);
    {
        const long long threads = (long long)TOT * 64;
        const int blocks = (int)((threads + 255) / 256);
        k_aggr<<<blocks, 256, 0, stream>>>(ei, asrc, adst, mm, ss, xh, refined);
    }
    k_final<<<(NN * (CC / 4) + 255) / 256, 256, 0, stream>>>(x, refined, bias, out);
}

// Round 2
// 740.576 us; speedup vs baseline: 1.6497x; 1.6497x over previous
//
#include <hip/hip_runtime.h>
#include <math.h>

#define NN 50000
#define EE 800000
#define TOT (EE + NN)          // 850000 edges incl. self loops
#define CC 128
#define HH 4
#define HCW 512                // H*C

// ---- monotone float<->uint mapping for atomicMax on signed floats ----
__device__ __forceinline__ unsigned f2mono(float f) {
    unsigned u = __float_as_uint(f);
    return (u & 0x80000000u) ? ~u : (u | 0x80000000u);
}
__device__ __forceinline__ float mono2f(unsigned m) {
    return (m & 0x80000000u) ? __uint_as_float(m ^ 0x80000000u)
                             : __uint_as_float(~m);
}
// fp32 -> bf16 bits, round-to-nearest-even
__device__ __forceinline__ unsigned short f2bf(float f) {
    unsigned u = __float_as_uint(f);
    unsigned r = (u + 0x7fffu + ((u >> 16) & 1u)) >> 16;
    return (unsigned short)r;
}
__device__ __forceinline__ float bfu2f(unsigned u16) {   // low 16 bits = bf16
    return __uint_as_float(u16 << 16);
}

// ---------------- K1: xh = x @ W (bf16 out), fused a_src/a_dst ----------------
__global__ __launch_bounds__(256) void k_gemm(
    const float* __restrict__ x, const float* __restrict__ W,
    const float* __restrict__ att_s, const float* __restrict__ att_d,
    unsigned short* __restrict__ xhb, float* __restrict__ asrc, float* __restrict__ adst)
{
    __shared__ float xs[32][CC];
    const int tid = threadIdx.x;
    const int block_row0 = blockIdx.x * 32;

    for (int i = tid; i < 32 * 32; i += 256) {
        int r  = i >> 5;
        int c4 = i & 31;
        int row = block_row0 + r;
        float4 v;
        if (row < NN) v = *(const float4*)(x + (size_t)row * CC + c4 * 4);
        else          v = make_float4(0.f, 0.f, 0.f, 0.f);
        *(float4*)(&xs[r][c4 * 4]) = v;
    }
    __syncthreads();

    const int wv   = tid >> 6;
    const int lane = tid & 63;
    const int r0   = wv * 8;
    const int row0 = block_row0 + r0;
    const int c0   = lane * 8;
    const int h    = c0 >> 7;
    const int hc0  = c0 & 127;

    const float4 s0 = *(const float4*)(att_s + h * CC + hc0);
    const float4 s1 = *(const float4*)(att_s + h * CC + hc0 + 4);
    const float4 d0 = *(const float4*)(att_d + h * CC + hc0);
    const float4 d1 = *(const float4*)(att_d + h * CC + hc0 + 4);

    float acc[8][8];
#pragma unroll
    for (int r = 0; r < 8; ++r)
#pragma unroll
        for (int j = 0; j < 8; ++j) acc[r][j] = 0.f;

#pragma unroll 4
    for (int k = 0; k < CC; ++k) {
        const float4 w0 = *(const float4*)(W + (size_t)k * HCW + c0);
        const float4 w1 = *(const float4*)(W + (size_t)k * HCW + c0 + 4);
#pragma unroll
        for (int r = 0; r < 8; ++r) {
            const float xv = xs[r0 + r][k];
            acc[r][0] += xv * w0.x; acc[r][1] += xv * w0.y;
            acc[r][2] += xv * w0.z; acc[r][3] += xv * w0.w;
            acc[r][4] += xv * w1.x; acc[r][5] += xv * w1.y;
            acc[r][6] += xv * w1.z; acc[r][7] += xv * w1.w;
        }
    }

#pragma unroll
    for (int r = 0; r < 8; ++r) {
        const int row = row0 + r;
        if (row >= NN) continue;
        // pack 8 fp32 -> 8 bf16 (16 B)
        unsigned p0 = (unsigned)f2bf(acc[r][0]) | ((unsigned)f2bf(acc[r][1]) << 16);
        unsigned p1 = (unsigned)f2bf(acc[r][2]) | ((unsigned)f2bf(acc[r][3]) << 16);
        unsigned p2 = (unsigned)f2bf(acc[r][4]) | ((unsigned)f2bf(acc[r][5]) << 16);
        unsigned p3 = (unsigned)f2bf(acc[r][6]) | ((unsigned)f2bf(acc[r][7]) << 16);
        uint4 pk = make_uint4(p0, p1, p2, p3);
        *(uint4*)(xhb + (size_t)row * HCW + c0) = pk;

        float ps = acc[r][0]*s0.x + acc[r][1]*s0.y + acc[r][2]*s0.z + acc[r][3]*s0.w
                 + acc[r][4]*s1.x + acc[r][5]*s1.y + acc[r][6]*s1.z + acc[r][7]*s1.w;
        float pd = acc[r][0]*d0.x + acc[r][1]*d0.y + acc[r][2]*d0.z + acc[r][3]*d0.w
                 + acc[r][4]*d1.x + acc[r][5]*d1.y + acc[r][6]*d1.z + acc[r][7]*d1.w;
#pragma unroll
        for (int off = 1; off < 16; off <<= 1) {
            ps += __shfl_xor(ps, off);
            pd += __shfl_xor(pd, off);
        }
        if ((lane & 15) == 0) {
            asrc[row * HH + h] = ps;
            adst[row * HH + h] = pd;
        }
    }
}

// -------- K2: segment max + degree count --------
__global__ __launch_bounds__(256) void k_edge_max(
    const int* __restrict__ ei, const float* __restrict__ asrc,
    const float* __restrict__ adst, unsigned* __restrict__ mm, int* __restrict__ deg)
{
    const int e = blockIdx.x * 256 + threadIdx.x;
    if (e >= TOT) return;
    int s, d;
    if (e < EE) { s = ei[e]; d = ei[EE + e]; } else { s = d = e - EE; }
    const float4 a = *(const float4*)(asrc + (size_t)s * HH);
    const float4 b = *(const float4*)(adst + (size_t)d * HH);
    float v0 = a.x + b.x; v0 = v0 > 0.f ? v0 : 0.2f * v0;
    float v1 = a.y + b.y; v1 = v1 > 0.f ? v1 : 0.2f * v1;
    float v2 = a.z + b.z; v2 = v2 > 0.f ? v2 : 0.2f * v2;
    float v3 = a.w + b.w; v3 = v3 > 0.f ? v3 : 0.2f * v3;
    atomicMax(mm + (size_t)d * HH + 0, f2mono(v0));
    atomicMax(mm + (size_t)d * HH + 1, f2mono(v1));
    atomicMax(mm + (size_t)d * HH + 2, f2mono(v2));
    atomicMax(mm + (size_t)d * HH + 3, f2mono(v3));
    atomicAdd(deg + d, 1);
}

// -------- K3: p = exp(e - m), segment sum --------
__global__ __launch_bounds__(256) void k_edge_sum(
    const int* __restrict__ ei, const float* __restrict__ asrc,
    const float* __restrict__ adst, const unsigned* __restrict__ mm,
    float* __restrict__ ss)
{
    const int e = blockIdx.x * 256 + threadIdx.x;
    if (e >= TOT) return;
    int s, d;
    if (e < EE) { s = ei[e]; d = ei[EE + e]; } else { s = d = e - EE; }
    const float4 a = *(const float4*)(asrc + (size_t)s * HH);
    const float4 b = *(const float4*)(adst + (size_t)d * HH);
    const uint4  m4 = *(const uint4*)(mm + (size_t)d * HH);
    float v0 = a.x + b.x; v0 = v0 > 0.f ? v0 : 0.2f * v0;
    float v1 = a.y + b.y; v1 = v1 > 0.f ? v1 : 0.2f * v1;
    float v2 = a.z + b.z; v2 = v2 > 0.f ? v2 : 0.2f * v2;
    float v3 = a.w + b.w; v3 = v3 > 0.f ? v3 : 0.2f * v3;
    atomicAdd(ss + (size_t)d * HH + 0, expf(v0 - mono2f(m4.x)));
    atomicAdd(ss + (size_t)d * HH + 1, expf(v1 - mono2f(m4.y)));
    atomicAdd(ss + (size_t)d * HH + 2, expf(v2 - mono2f(m4.z)));
    atomicAdd(ss + (size_t)d * HH + 3, expf(v3 - mono2f(m4.w)));
}

// -------- K4: exclusive scan of deg -> rowptr, cursor (single block) --------
__global__ __launch_bounds__(1024) void k_scan(
    const int* __restrict__ deg, int* __restrict__ rowptr, int* __restrict__ cursor)
{
    __shared__ int sm[1024];
    const int t = threadIdx.x;
    const int CH = (NN + 1023) / 1024;   // 49
    const int base = t * CH;
    int sum = 0;
    for (int i = 0; i < CH; ++i) {
        int idx = base + i;
        if (idx < NN) sum += deg[idx];
    }
    sm[t] = sum;
    __syncthreads();
    for (int off = 1; off < 1024; off <<= 1) {
        int v = (t >= off) ? sm[t - off] : 0;
        __syncthreads();
        sm[t] += v;
        __syncthreads();
    }
    int run = (t > 0) ? sm[t - 1] : 0;
    for (int i = 0; i < CH; ++i) {
        int idx = base + i;
        if (idx < NN) {
            rowptr[idx] = run;
            cursor[idx] = run;
            run += deg[idx];
        }
    }
    if (t == 0) rowptr[NN] = TOT;
}

// -------- K5: scatter edges into dst-sorted CSR with final weights --------
__global__ __launch_bounds__(256) void k_scatter(
    const int* __restrict__ ei, const float* __restrict__ asrc,
    const float* __restrict__ adst, const unsigned* __restrict__ mm,
    const float* __restrict__ ss, int* __restrict__ cursor,
    int* __restrict__ csr_src, float4* __restrict__ csr_w)
{
    const int e = blockIdx.x * 256 + threadIdx.x;
    if (e >= TOT) return;
    int s, d;
    if (e < EE) { s = ei[e]; d = ei[EE + e]; } else { s = d = e - EE; }
    const float4 a  = *(const float4*)(asrc + (size_t)s * HH);
    const float4 b  = *(const float4*)(adst + (size_t)d * HH);
    const uint4  m4 = *(const uint4*)(mm + (size_t)d * HH);
    const float4 s4 = *(const float4*)(ss + (size_t)d * HH);
    float4 w;
    float v;
    v = a.x + b.x; v = v > 0.f ? v : 0.2f * v;
    w.x = expf(v - mono2f(m4.x)) / (s4.x + 1e-16f) * 0.25f;
    v = a.y + b.y; v = v > 0.f ? v : 0.2f * v;
    w.y = expf(v - mono2f(m4.y)) / (s4.y + 1e-16f) * 0.25f;
    v = a.z + b.z; v = v > 0.f ? v : 0.2f * v;
    w.z = expf(v - mono2f(m4.z)) / (s4.z + 1e-16f) * 0.25f;
    v = a.w + b.w; v = v > 0.f ? v : 0.2f * v;
    w.w = expf(v - mono2f(m4.w)) / (s4.w + 1e-16f) * 0.25f;
    const int pos = atomicAdd(cursor + d, 1);
    csr_src[pos] = s;
    csr_w[pos]   = w;
}

// -------- K6: per-node gather + head-mean + residual blend (one wave/node) ----
__global__ __launch_bounds__(256) void k_gather(
    const int* __restrict__ rowptr, const int* __restrict__ csr_src,
    const float4* __restrict__ csr_w, const unsigned* __restrict__ xhb32,
    const float* __restrict__ x, const float* __restrict__ bias,
    float* __restrict__ out)
{
    const int gtid = blockIdx.x * 256 + threadIdx.x;
    const int n    = gtid >> 6;
    const int lane = threadIdx.x & 63;
    if (n >= NN) return;

    const int beg = rowptr[n];
    const int end = rowptr[n + 1];

    float r0 = 0.f, r1 = 0.f;
    for (int j = beg; j < end; ++j) {
        const int    s = csr_src[j];
        const float4 w = csr_w[j];
        const unsigned* p = xhb32 + (size_t)s * (HCW / 2) + lane;  // 2 bf16 per u32
        const unsigned q0 = p[0];
        const unsigned q1 = p[64];
        const unsigned q2 = p[128];
        const unsigned q3 = p[192];
        r0 += w.x * bfu2f(q0 & 0xffffu) + w.y * bfu2f(q1 & 0xffffu)
            + w.z * bfu2f(q2 & 0xffffu) + w.w * bfu2f(q3 & 0xffffu);
        r1 += w.x * bfu2f(q0 >> 16) + w.y * bfu2f(q1 >> 16)
            + w.z * bfu2f(q2 >> 16) + w.w * bfu2f(q3 >> 16);
    }

    const int c = lane * 2;
    const float2 xv = *(const float2*)(x + (size_t)n * CC + c);
    const float2 bv = *(const float2*)(bias + c);
    float2 o;
    o.x = 0.8f * xv.x + 0.2f * (r0 + bv.x);
    o.y = 0.8f * xv.y + 0.2f * (r1 + bv.y);
    *(float2*)(out + (size_t)n * CC + c) = o;
}

extern "C" void kernel_launch(void* const* d_in, const int* in_sizes, int n_in,
                              void* d_out, int out_size, void* d_ws, size_t ws_size,
                              hipStream_t stream)
{
    const float* x     = (const float*)d_in[0];
    const int*   ei    = (const int*)d_in[1];
    const float* W     = (const float*)d_in[2];
    const float* att_s = (const float*)d_in[3];
    const float* att_d = (const float*)d_in[4];
    const float* bias  = (const float*)d_in[5];
    float* out = (float*)d_out;

    char* p = (char*)d_ws;
    unsigned short* xhb   = (unsigned short*)p; p += (size_t)NN * HCW * 2;  // 51.2 MB
    float4*         csr_w = (float4*)p;         p += (size_t)TOT * 16;      // 13.6 MB
    float*          asrc  = (float*)p;          p += (size_t)NN * HH * 4;
    float*          adst  = (float*)p;          p += (size_t)NN * HH * 4;
    unsigned*       mm    = (unsigned*)p;       p += (size_t)NN * HH * 4;   // zeroed
    float*          ss    = (float*)p;          p += (size_t)NN * HH * 4;   // zeroed
    int*            deg   = (int*)p;            p += (size_t)NN * 4;        // zeroed
    int*            cursor= (int*)p;            p += (size_t)NN * 4;
    int*            csr_s = (int*)p;            p += (size_t)TOT * 4;
    int*            rowptr= (int*)p;            p += (size_t)(NN + 1) * 4;

    // zero mm, ss, deg (contiguous)
    hipMemsetAsync(mm, 0, (size_t)(NN * HH * 2 + NN) * 4, stream);

    k_gemm<<<(NN + 31) / 32, 256, 0, stream>>>(x, W, att_s, att_d, xhb, asrc, adst);
    k_edge_max<<<(TOT + 255) / 256, 256, 0, stream>>>(ei, asrc, adst, mm, deg);
    k_edge_sum<<<(TOT + 255) / 256, 256, 0, stream>>>(ei, asrc, adst, mm, ss);
    k_scan<<<1, 1024, 0, stream>>>(deg, rowptr, cursor);
    k_scatter<<<(TOT + 255) / 256, 256, 0, stream>>>(ei, asrc, adst, mm, ss, cursor, csr_s, csr_w);
    {
        const long long threads = (long long)NN * 64;
        const int blocks = (int)((threads + 255) / 256);
        k_gather<<<blocks, 256, 0, stream>>>(rowptr, csr_s, csr_w, (const unsigned*)xhb, x, bias, out);
    }
}

// Round 3
// 445.854 us; speedup vs baseline: 2.7402x; 1.6610x over previous
//
#include <hip/hip_runtime.h>
#include <math.h>

#define NN 50000
#define EE 800000
#define TOT (EE + NN)          // 850000 edges incl. self loops
#define CC 128
#define HH 4
#define HCW 512                // H*C

// fp32 -> bf16 bits, round-to-nearest-even
__device__ __forceinline__ unsigned short f2bf(float f) {
    unsigned u = __float_as_uint(f);
    unsigned r = (u + 0x7fffu + ((u >> 16) & 1u)) >> 16;
    return (unsigned short)r;
}
__device__ __forceinline__ float bfu2f(unsigned u16) {   // low 16 bits = bf16
    return __uint_as_float(u16 << 16);
}

// ---------------- K1: xh = x @ W (bf16 out), fused a_src/a_dst ----------------
__global__ __launch_bounds__(256) void k_gemm(
    const float* __restrict__ x, const float* __restrict__ W,
    const float* __restrict__ att_s, const float* __restrict__ att_d,
    unsigned short* __restrict__ xhb, float* __restrict__ asrc, float* __restrict__ adst)
{
    __shared__ float xs[32][CC];
    const int tid = threadIdx.x;
    const int block_row0 = blockIdx.x * 32;

    for (int i = tid; i < 32 * 32; i += 256) {
        int r  = i >> 5;
        int c4 = i & 31;
        int row = block_row0 + r;
        float4 v;
        if (row < NN) v = *(const float4*)(x + (size_t)row * CC + c4 * 4);
        else          v = make_float4(0.f, 0.f, 0.f, 0.f);
        *(float4*)(&xs[r][c4 * 4]) = v;
    }
    __syncthreads();

    const int wv   = tid >> 6;
    const int lane = tid & 63;
    const int r0   = wv * 8;
    const int row0 = block_row0 + r0;
    const int c0   = lane * 8;
    const int h    = c0 >> 7;
    const int hc0  = c0 & 127;

    const float4 s0 = *(const float4*)(att_s + h * CC + hc0);
    const float4 s1 = *(const float4*)(att_s + h * CC + hc0 + 4);
    const float4 d0 = *(const float4*)(att_d + h * CC + hc0);
    const float4 d1 = *(const float4*)(att_d + h * CC + hc0 + 4);

    float acc[8][8];
#pragma unroll
    for (int r = 0; r < 8; ++r)
#pragma unroll
        for (int j = 0; j < 8; ++j) acc[r][j] = 0.f;

#pragma unroll 4
    for (int k = 0; k < CC; ++k) {
        const float4 w0 = *(const float4*)(W + (size_t)k * HCW + c0);
        const float4 w1 = *(const float4*)(W + (size_t)k * HCW + c0 + 4);
#pragma unroll
        for (int r = 0; r < 8; ++r) {
            const float xv = xs[r0 + r][k];
            acc[r][0] += xv * w0.x; acc[r][1] += xv * w0.y;
            acc[r][2] += xv * w0.z; acc[r][3] += xv * w0.w;
            acc[r][4] += xv * w1.x; acc[r][5] += xv * w1.y;
            acc[r][6] += xv * w1.z; acc[r][7] += xv * w1.w;
        }
    }

#pragma unroll
    for (int r = 0; r < 8; ++r) {
        const int row = row0 + r;
        if (row >= NN) continue;
        unsigned p0 = (unsigned)f2bf(acc[r][0]) | ((unsigned)f2bf(acc[r][1]) << 16);
        unsigned p1 = (unsigned)f2bf(acc[r][2]) | ((unsigned)f2bf(acc[r][3]) << 16);
        unsigned p2 = (unsigned)f2bf(acc[r][4]) | ((unsigned)f2bf(acc[r][5]) << 16);
        unsigned p3 = (unsigned)f2bf(acc[r][6]) | ((unsigned)f2bf(acc[r][7]) << 16);
        uint4 pk = make_uint4(p0, p1, p2, p3);
        *(uint4*)(xhb + (size_t)row * HCW + c0) = pk;

        float ps = acc[r][0]*s0.x + acc[r][1]*s0.y + acc[r][2]*s0.z + acc[r][3]*s0.w
                 + acc[r][4]*s1.x + acc[r][5]*s1.y + acc[r][6]*s1.z + acc[r][7]*s1.w;
        float pd = acc[r][0]*d0.x + acc[r][1]*d0.y + acc[r][2]*d0.z + acc[r][3]*d0.w
                 + acc[r][4]*d1.x + acc[r][5]*d1.y + acc[r][6]*d1.z + acc[r][7]*d1.w;
#pragma unroll
        for (int off = 1; off < 16; off <<= 1) {
            ps += __shfl_xor(ps, off);
            pd += __shfl_xor(pd, off);
        }
        if ((lane & 15) == 0) {
            asrc[row * HH + h] = ps;
            adst[row * HH + h] = pd;
        }
    }
}

// -------- K2: degree count (1 int atomic per edge) --------
__global__ __launch_bounds__(256) void k_count(
    const int* __restrict__ ei, int* __restrict__ deg)
{
    const int e = blockIdx.x * 256 + threadIdx.x;
    if (e >= TOT) return;
    const int d = (e < EE) ? ei[EE + e] : (e - EE);
    atomicAdd(deg + d, 1);
}

// -------- K3: exclusive scan of deg -> rowptr, cursor (single block) --------
__global__ __launch_bounds__(1024) void k_scan(
    const int* __restrict__ deg, int* __restrict__ rowptr, int* __restrict__ cursor)
{
    __shared__ int sm[1024];
    const int t = threadIdx.x;
    const int CH = (NN + 1023) / 1024;   // 49
    const int base = t * CH;
    int sum = 0;
    for (int i = 0; i < CH; ++i) {
        int idx = base + i;
        if (idx < NN) sum += deg[idx];
    }
    sm[t] = sum;
    __syncthreads();
    for (int off = 1; off < 1024; off <<= 1) {
        int v = (t >= off) ? sm[t - off] : 0;
        __syncthreads();
        sm[t] += v;
        __syncthreads();
    }
    int run = (t > 0) ? sm[t - 1] : 0;
    for (int i = 0; i < CH; ++i) {
        int idx = base + i;
        if (idx < NN) {
            rowptr[idx] = run;
            cursor[idx] = run;
            run += deg[idx];
        }
    }
    if (t == 0) rowptr[NN] = TOT;
}

// -------- K4: scatter edges into dst-sorted CSR with RAW leaky scores --------
__global__ __launch_bounds__(256) void k_scatter(
    const int* __restrict__ ei, const float* __restrict__ asrc,
    const float* __restrict__ adst, int* __restrict__ cursor,
    int* __restrict__ csr_src, float4* __restrict__ csr_e)
{
    const int e = blockIdx.x * 256 + threadIdx.x;
    if (e >= TOT) return;
    int s, d;
    if (e < EE) { s = ei[e]; d = ei[EE + e]; } else { s = d = e - EE; }
    const float4 a = *(const float4*)(asrc + (size_t)s * HH);
    const float4 b = *(const float4*)(adst + (size_t)d * HH);
    float4 v;
    v.x = a.x + b.x; v.x = v.x > 0.f ? v.x : 0.2f * v.x;
    v.y = a.y + b.y; v.y = v.y > 0.f ? v.y : 0.2f * v.y;
    v.z = a.z + b.z; v.z = v.z > 0.f ? v.z : 0.2f * v.z;
    v.w = a.w + b.w; v.w = v.w > 0.f ? v.w : 0.2f * v.w;
    const int pos = atomicAdd(cursor + d, 1);
    csr_src[pos] = s;
    csr_e[pos]   = v;
}

// -------- K5: fused per-node softmax + gather + residual (one wave/node) ----
__global__ __launch_bounds__(256) void k_gather(
    const int* __restrict__ rowptr, const int* __restrict__ csr_src,
    const float4* __restrict__ csr_e, const unsigned* __restrict__ xhb32,
    const float* __restrict__ x, const float* __restrict__ bias,
    float* __restrict__ out)
{
    const int gtid = blockIdx.x * 256 + threadIdx.x;
    const int n    = gtid >> 6;
    const int lane = threadIdx.x & 63;
    if (n >= NN) return;

    const int beg = rowptr[n];
    const int end = rowptr[n + 1];

    // ---- phase 1: online softmax stats per head, lane-strided ----
    float m0 = -1e30f, m1 = -1e30f, m2 = -1e30f, m3 = -1e30f;
    float s0 = 0.f, s1 = 0.f, s2 = 0.f, s3 = 0.f;
    for (int j = beg + lane; j < end; j += 64) {
        const float4 e = csr_e[j];
        float nm;
        nm = fmaxf(m0, e.x); s0 = s0 * __expf(m0 - nm) + __expf(e.x - nm); m0 = nm;
        nm = fmaxf(m1, e.y); s1 = s1 * __expf(m1 - nm) + __expf(e.y - nm); m1 = nm;
        nm = fmaxf(m2, e.z); s2 = s2 * __expf(m2 - nm) + __expf(e.z - nm); m2 = nm;
        nm = fmaxf(m3, e.w); s3 = s3 * __expf(m3 - nm) + __expf(e.w - nm); m3 = nm;
    }
    // butterfly combine across 64 lanes (NaN-safe: sentinel is finite)
#pragma unroll
    for (int off = 1; off < 64; off <<= 1) {
        float om, os, nm;
        om = __shfl_xor(m0, off); os = __shfl_xor(s0, off);
        nm = fmaxf(m0, om); s0 = s0 * __expf(m0 - nm) + os * __expf(om - nm); m0 = nm;
        om = __shfl_xor(m1, off); os = __shfl_xor(s1, off);
        nm = fmaxf(m1, om); s1 = s1 * __expf(m1 - nm) + os * __expf(om - nm); m1 = nm;
        om = __shfl_xor(m2, off); os = __shfl_xor(s2, off);
        nm = fmaxf(m2, om); s2 = s2 * __expf(m2 - nm) + os * __expf(om - nm); m2 = nm;
        om = __shfl_xor(m3, off); os = __shfl_xor(s3, off);
        nm = fmaxf(m3, om); s3 = s3 * __expf(m3 - nm) + os * __expf(om - nm); m3 = nm;
    }
    const float i0 = 0.25f / (s0 + 1e-16f);
    const float i1 = 0.25f / (s1 + 1e-16f);
    const float i2 = 0.25f / (s2 + 1e-16f);
    const float i3 = 0.25f / (s3 + 1e-16f);

    // ---- phase 2: weighted gather; lane owns channels 2*lane, 2*lane+1 ----
    float r0 = 0.f, r1 = 0.f;
    for (int j = beg; j < end; ++j) {
        const int    s = csr_src[j];
        const float4 e = csr_e[j];
        const float w0 = __expf(e.x - m0) * i0;
        const float w1 = __expf(e.y - m1) * i1;
        const float w2 = __expf(e.z - m2) * i2;
        const float w3 = __expf(e.w - m3) * i3;
        const unsigned* p = xhb32 + (size_t)s * (HCW / 2) + lane;
        const unsigned q0 = p[0];
        const unsigned q1 = p[64];
        const unsigned q2 = p[128];
        const unsigned q3 = p[192];
        r0 += w0 * bfu2f(q0 & 0xffffu) + w1 * bfu2f(q1 & 0xffffu)
            + w2 * bfu2f(q2 & 0xffffu) + w3 * bfu2f(q3 & 0xffffu);
        r1 += w0 * bfu2f(q0 >> 16) + w1 * bfu2f(q1 >> 16)
            + w2 * bfu2f(q2 >> 16) + w3 * bfu2f(q3 >> 16);
    }

    const int c = lane * 2;
    const float2 xv = *(const float2*)(x + (size_t)n * CC + c);
    const float2 bv = *(const float2*)(bias + c);
    float2 o;
    o.x = 0.8f * xv.x + 0.2f * (r0 + bv.x);
    o.y = 0.8f * xv.y + 0.2f * (r1 + bv.y);
    *(float2*)(out + (size_t)n * CC + c) = o;
}

extern "C" void kernel_launch(void* const* d_in, const int* in_sizes, int n_in,
                              void* d_out, int out_size, void* d_ws, size_t ws_size,
                              hipStream_t stream)
{
    const float* x     = (const float*)d_in[0];
    const int*   ei    = (const int*)d_in[1];
    const float* W     = (const float*)d_in[2];
    const float* att_s = (const float*)d_in[3];
    const float* att_d = (const float*)d_in[4];
    const float* bias  = (const float*)d_in[5];
    float* out = (float*)d_out;

    char* p = (char*)d_ws;
    unsigned short* xhb   = (unsigned short*)p; p += (size_t)NN * HCW * 2;  // 51.2 MB
    float4*         csr_e = (float4*)p;         p += (size_t)TOT * 16;      // 13.6 MB
    float*          asrc  = (float*)p;          p += (size_t)NN * HH * 4;
    float*          adst  = (float*)p;          p += (size_t)NN * HH * 4;
    int*            deg   = (int*)p;            p += (size_t)NN * 4;        // zeroed
    int*            cursor= (int*)p;            p += (size_t)NN * 4;
    int*            csr_s = (int*)p;            p += (size_t)TOT * 4;
    int*            rowptr= (int*)p;            p += (size_t)(NN + 1) * 4;

    hipMemsetAsync(deg, 0, (size_t)NN * 4, stream);

    k_gemm<<<(NN + 31) / 32, 256, 0, stream>>>(x, W, att_s, att_d, xhb, asrc, adst);
    k_count<<<(TOT + 255) / 256, 256, 0, stream>>>(ei, deg);
    k_scan<<<1, 1024, 0, stream>>>(deg, rowptr, cursor);
    k_scatter<<<(TOT + 255) / 256, 256, 0, stream>>>(ei, asrc, adst, cursor, csr_s, csr_e);
    {
        const long long threads = (long long)NN * 64;
        const int blocks = (int)((threads + 255) / 256);
        k_gather<<<blocks, 256, 0, stream>>>(rowptr, csr_s, csr_e, (const unsigned*)xhb, x, bias, out);
    }
}

// Round 4
// 422.087 us; speedup vs baseline: 2.8945x; 1.0563x over previous
//
#include <hip/hip_runtime.h>
#include <math.h>

#define NN 50000
#define EE 800000
#define TOT (EE + NN)          // 850000 edges incl. self loops
#define CC 128
#define HH 4
#define HCW 512                // H*C

typedef short s16x8 __attribute__((ext_vector_type(8)));
typedef float f32x4 __attribute__((ext_vector_type(4)));

// fp32 -> bf16 bits, round-to-nearest-even
__device__ __forceinline__ unsigned short f2bf(float f) {
    unsigned u = __float_as_uint(f);
    unsigned r = (u + 0x7fffu + ((u >> 16) & 1u)) >> 16;
    return (unsigned short)r;
}
__device__ __forceinline__ float bf_lo(unsigned q) { return __uint_as_float(q << 16); }
__device__ __forceinline__ float bf_hi(unsigned q) { return __uint_as_float(q & 0xffff0000u); }

__device__ __forceinline__ unsigned short f2h_bits(float f) {
    union { _Float16 h; unsigned short u; } cv;
    cv.h = (_Float16)f;
    return cv.u;
}
__device__ __forceinline__ float h2f(unsigned short u) {
    union { _Float16 h; unsigned short u; } cv;
    cv.u = u;
    return (float)cv.h;
}

// -------- P1: x fp32 -> bf16 (8 elems/thread) --------
__global__ __launch_bounds__(256) void k_prep_x(
    const float* __restrict__ x, unsigned short* __restrict__ xb)
{
    const int i = blockIdx.x * 256 + threadIdx.x;
    if (i >= NN * CC / 8) return;
    const float4 v0 = ((const float4*)x)[i * 2];
    const float4 v1 = ((const float4*)x)[i * 2 + 1];
    uint4 o;
    o.x = (unsigned)f2bf(v0.x) | ((unsigned)f2bf(v0.y) << 16);
    o.y = (unsigned)f2bf(v0.z) | ((unsigned)f2bf(v0.w) << 16);
    o.z = (unsigned)f2bf(v1.x) | ((unsigned)f2bf(v1.y) << 16);
    o.w = (unsigned)f2bf(v1.z) | ((unsigned)f2bf(v1.w) << 16);
    ((uint4*)xb)[i] = o;
}

// -------- P2: W [128][512] fp32 -> Wt [512][128] bf16 --------
__global__ __launch_bounds__(256) void k_prep_w(
    const float* __restrict__ W, unsigned short* __restrict__ wt)
{
    const int i = blockIdx.x * 256 + threadIdx.x;   // i = c*128 + k
    if (i >= HCW * CC) return;
    const int c = i >> 7, k = i & 127;
    wt[i] = f2bf(W[(size_t)k * HCW + c]);
}

// -------- K1: xh = x @ W via MFMA bf16 --------
// grid (NN/16, 4 heads), block 128 (2 waves). Wave covers 16 rows x 64 cols.
__global__ __launch_bounds__(128) void k_gemm(
    const unsigned short* __restrict__ xb,   // [NN][128] bf16
    const unsigned short* __restrict__ wt,   // [512][128] bf16 = W^T
    unsigned short* __restrict__ xhb)        // [NN][512] bf16
{
    const int r0   = blockIdx.x * 16;
    const int h    = blockIdx.y;
    const int wave = threadIdx.x >> 6;
    const int lane = threadIdx.x & 63;
    const int lrow = lane & 15;
    const int kgrp = lane >> 4;
    const int n_base = h * 128 + wave * 64;

    f32x4 acc0 = {0.f, 0.f, 0.f, 0.f};
    f32x4 acc1 = {0.f, 0.f, 0.f, 0.f};
    f32x4 acc2 = {0.f, 0.f, 0.f, 0.f};
    f32x4 acc3 = {0.f, 0.f, 0.f, 0.f};

    const unsigned short* arow = xb + (size_t)(r0 + lrow) * CC + kgrp * 8;
    const unsigned short* b0p  = wt + (size_t)(n_base + 0  + lrow) * CC + kgrp * 8;
    const unsigned short* b1p  = wt + (size_t)(n_base + 16 + lrow) * CC + kgrp * 8;
    const unsigned short* b2p  = wt + (size_t)(n_base + 32 + lrow) * CC + kgrp * 8;
    const unsigned short* b3p  = wt + (size_t)(n_base + 48 + lrow) * CC + kgrp * 8;

#pragma unroll
    for (int kk = 0; kk < 4; ++kk) {
        const s16x8 a  = *(const s16x8*)(arow + kk * 32);
        const s16x8 b0 = *(const s16x8*)(b0p  + kk * 32);
        const s16x8 b1 = *(const s16x8*)(b1p  + kk * 32);
        const s16x8 b2 = *(const s16x8*)(b2p  + kk * 32);
        const s16x8 b3 = *(const s16x8*)(b3p  + kk * 32);
        acc0 = __builtin_amdgcn_mfma_f32_16x16x32_bf16(a, b0, acc0, 0, 0, 0);
        acc1 = __builtin_amdgcn_mfma_f32_16x16x32_bf16(a, b1, acc1, 0, 0, 0);
        acc2 = __builtin_amdgcn_mfma_f32_16x16x32_bf16(a, b2, acc2, 0, 0, 0);
        acc3 = __builtin_amdgcn_mfma_f32_16x16x32_bf16(a, b3, acc3, 0, 0, 0);
    }

    // D: row = (lane>>4)*4 + reg, col = lane&15  (per tile)
#pragma unroll
    for (int r = 0; r < 4; ++r) {
        const size_t row = (size_t)(r0 + kgrp * 4 + r) * HCW;
        xhb[row + n_base + 0  + lrow] = f2bf(acc0[r]);
        xhb[row + n_base + 16 + lrow] = f2bf(acc1[r]);
        xhb[row + n_base + 32 + lrow] = f2bf(acc2[r]);
        xhb[row + n_base + 48 + lrow] = f2bf(acc3[r]);
    }
}

// -------- K2: a_src/a_dst from xhb (one wave per node) --------
__global__ __launch_bounds__(256) void k_att(
    const unsigned short* __restrict__ xhb, const float* __restrict__ att_s,
    const float* __restrict__ att_d, float* __restrict__ asrc, float* __restrict__ adst)
{
    const int gtid = blockIdx.x * 256 + threadIdx.x;
    const int n    = gtid >> 6;
    const int lane = threadIdx.x & 63;
    if (n >= NN) return;

    const uint4 q = *(const uint4*)(xhb + (size_t)n * HCW + lane * 8);
    float xv0 = bf_lo(q.x), xv1 = bf_hi(q.x), xv2 = bf_lo(q.y), xv3 = bf_hi(q.y);
    float xv4 = bf_lo(q.z), xv5 = bf_hi(q.z), xv6 = bf_lo(q.w), xv7 = bf_hi(q.w);

    const float4 s0 = *(const float4*)(att_s + lane * 8);
    const float4 s1 = *(const float4*)(att_s + lane * 8 + 4);
    const float4 d0 = *(const float4*)(att_d + lane * 8);
    const float4 d1 = *(const float4*)(att_d + lane * 8 + 4);

    float ps = xv0*s0.x + xv1*s0.y + xv2*s0.z + xv3*s0.w
             + xv4*s1.x + xv5*s1.y + xv6*s1.z + xv7*s1.w;
    float pd = xv0*d0.x + xv1*d0.y + xv2*d0.z + xv3*d0.w
             + xv4*d1.x + xv5*d1.y + xv6*d1.z + xv7*d1.w;
#pragma unroll
    for (int off = 1; off < 16; off <<= 1) {
        ps += __shfl_xor(ps, off);
        pd += __shfl_xor(pd, off);
    }
    if ((lane & 15) == 0) {
        const int h = lane >> 4;
        asrc[n * HH + h] = ps;
        adst[n * HH + h] = pd;
    }
}

// -------- K3: degree count --------
__global__ __launch_bounds__(256) void k_count(
    const int* __restrict__ ei, int* __restrict__ deg)
{
    const int e = blockIdx.x * 256 + threadIdx.x;
    if (e >= TOT) return;
    const int d = (e < EE) ? ei[EE + e] : (e - EE);
    atomicAdd(deg + d, 1);
}

// -------- K4: exclusive scan of deg -> rowptr, cursor (single block) --------
__global__ __launch_bounds__(1024) void k_scan(
    const int* __restrict__ deg, int* __restrict__ rowptr, int* __restrict__ cursor)
{
    __shared__ int sm[1024];
    const int t = threadIdx.x;
    const int CH = (NN + 1023) / 1024;   // 49
    const int base = t * CH;
    int sum = 0;
    for (int i = 0; i < CH; ++i) {
        int idx = base + i;
        if (idx < NN) sum += deg[idx];
    }
    sm[t] = sum;
    __syncthreads();
    for (int off = 1; off < 1024; off <<= 1) {
        int v = (t >= off) ? sm[t - off] : 0;
        __syncthreads();
        sm[t] += v;
        __syncthreads();
    }
    int run = (t > 0) ? sm[t - 1] : 0;
    for (int i = 0; i < CH; ++i) {
        int idx = base + i;
        if (idx < NN) {
            rowptr[idx] = run;
            cursor[idx] = run;
            run += deg[idx];
        }
    }
    if (t == 0) rowptr[NN] = TOT;
}

// -------- K5: scatter edges into dst-sorted CSR, scores as fp16x4 --------
__global__ __launch_bounds__(256) void k_scatter(
    const int* __restrict__ ei, const float* __restrict__ asrc,
    const float* __restrict__ adst, int* __restrict__ cursor,
    int* __restrict__ csr_src, uint2* __restrict__ csr_e)
{
    const int e = blockIdx.x * 256 + threadIdx.x;
    if (e >= TOT) return;
    int s, d;
    if (e < EE) { s = ei[e]; d = ei[EE + e]; } else { s = d = e - EE; }
    const float4 a = *(const float4*)(asrc + (size_t)s * HH);
    const float4 b = *(const float4*)(adst + (size_t)d * HH);
    float4 v;
    v.x = a.x + b.x; v.x = v.x > 0.f ? v.x : 0.2f * v.x;
    v.y = a.y + b.y; v.y = v.y > 0.f ? v.y : 0.2f * v.y;
    v.z = a.z + b.z; v.z = v.z > 0.f ? v.z : 0.2f * v.z;
    v.w = a.w + b.w; v.w = v.w > 0.f ? v.w : 0.2f * v.w;
    uint2 rec;
    rec.x = (unsigned)f2h_bits(v.x) | ((unsigned)f2h_bits(v.y) << 16);
    rec.y = (unsigned)f2h_bits(v.z) | ((unsigned)f2h_bits(v.w) << 16);
    const int pos = atomicAdd(cursor + d, 1);
    csr_src[pos] = s;
    csr_e[pos]   = rec;
}

// -------- K6: fused softmax + gather + residual; head-major lanes --------
// lane = h*16 + t: owns channels h*128 + t*8 .. +7  (== uint4 index `lane` in xh row)
__global__ __launch_bounds__(256) void k_gather(
    const int* __restrict__ rowptr, const int* __restrict__ csr_src,
    const uint2* __restrict__ csr_e, const uint4* __restrict__ xhb4,
    const float* __restrict__ x, const float* __restrict__ bias,
    float* __restrict__ out)
{
    const int gtid = blockIdx.x * 256 + threadIdx.x;
    const int n    = gtid >> 6;
    const int lane = threadIdx.x & 63;
    if (n >= NN) return;
    const int h = lane >> 4;
    const int t = lane & 15;

    const int beg = rowptr[n];
    const int end = rowptr[n + 1];

    // phase 1: online softmax for head h; lanes stride the edge list by 16
    float m = -1e30f, ssum = 0.f;
    for (int j = beg + t; j < end; j += 16) {
        const uint2 ee = csr_e[j];
        const unsigned wsel = (h & 2) ? ee.y : ee.x;
        const unsigned short us = (h & 1) ? (unsigned short)(wsel >> 16)
                                          : (unsigned short)(wsel & 0xffffu);
        const float e = h2f(us);
        const float nm = fmaxf(m, e);
        ssum = ssum * __expf(m - nm) + __expf(e - nm);
        m = nm;
    }
#pragma unroll
    for (int off = 1; off < 16; off <<= 1) {
        const float om = __shfl_xor(m, off);
        const float os = __shfl_xor(ssum, off);
        const float nm = fmaxf(m, om);
        ssum = ssum * __expf(m - nm) + os * __expf(om - nm);
        m = nm;
    }
    const float inv = 0.25f / (ssum + 1e-16f);

    // phase 2: weighted gather (1 exp + 1 dwordx4 per edge per lane)
    float r0 = 0.f, r1 = 0.f, r2 = 0.f, r3 = 0.f;
    float r4 = 0.f, r5 = 0.f, r6 = 0.f, r7 = 0.f;
    for (int j = beg; j < end; ++j) {
        const int  s  = csr_src[j];
        const uint2 ee = csr_e[j];
        const unsigned wsel = (h & 2) ? ee.y : ee.x;
        const unsigned short us = (h & 1) ? (unsigned short)(wsel >> 16)
                                          : (unsigned short)(wsel & 0xffffu);
        const float w = __expf(h2f(us) - m) * inv;
        const uint4 q = xhb4[(size_t)s * 64 + lane];
        r0 += w * bf_lo(q.x); r1 += w * bf_hi(q.x);
        r2 += w * bf_lo(q.y); r3 += w * bf_hi(q.y);
        r4 += w * bf_lo(q.z); r5 += w * bf_hi(q.z);
        r6 += w * bf_lo(q.w); r7 += w * bf_hi(q.w);
    }

    // sum across the 4 head groups (lanes differ in bits 4..5)
#pragma unroll
    for (int off = 16; off < 64; off <<= 1) {
        r0 += __shfl_xor(r0, off); r1 += __shfl_xor(r1, off);
        r2 += __shfl_xor(r2, off); r3 += __shfl_xor(r3, off);
        r4 += __shfl_xor(r4, off); r5 += __shfl_xor(r5, off);
        r6 += __shfl_xor(r6, off); r7 += __shfl_xor(r7, off);
    }

    if (h == 0) {
        const int c = t * 8;
        const float4 x0 = *(const float4*)(x + (size_t)n * CC + c);
        const float4 x1 = *(const float4*)(x + (size_t)n * CC + c + 4);
        const float4 b0 = *(const float4*)(bias + c);
        const float4 b1 = *(const float4*)(bias + c + 4);
        float4 o0, o1;
        o0.x = 0.8f * x0.x + 0.2f * (r0 + b0.x);
        o0.y = 0.8f * x0.y + 0.2f * (r1 + b0.y);
        o0.z = 0.8f * x0.z + 0.2f * (r2 + b0.z);
        o0.w = 0.8f * x0.w + 0.2f * (r3 + b0.w);
        o1.x = 0.8f * x1.x + 0.2f * (r4 + b1.x);
        o1.y = 0.8f * x1.y + 0.2f * (r5 + b1.y);
        o1.z = 0.8f * x1.z + 0.2f * (r6 + b1.z);
        o1.w = 0.8f * x1.w + 0.2f * (r7 + b1.w);
        *(float4*)(out + (size_t)n * CC + c)     = o0;
        *(float4*)(out + (size_t)n * CC + c + 4) = o1;
    }
}

extern "C" void kernel_launch(void* const* d_in, const int* in_sizes, int n_in,
                              void* d_out, int out_size, void* d_ws, size_t ws_size,
                              hipStream_t stream)
{
    const float* x     = (const float*)d_in[0];
    const int*   ei    = (const int*)d_in[1];
    const float* W     = (const float*)d_in[2];
    const float* att_s = (const float*)d_in[3];
    const float* att_d = (const float*)d_in[4];
    const float* bias  = (const float*)d_in[5];
    float* out = (float*)d_out;

    char* p = (char*)d_ws;
    unsigned short* xhb   = (unsigned short*)p; p += (size_t)NN * HCW * 2;  // 51.2 MB
    unsigned short* xb    = (unsigned short*)p; p += (size_t)NN * CC * 2;   // 12.8 MB
    unsigned short* wt    = (unsigned short*)p; p += (size_t)HCW * CC * 2;  // 128 KB
    uint2*          csr_e = (uint2*)p;          p += (size_t)TOT * 8;       // 6.8 MB
    float*          asrc  = (float*)p;          p += (size_t)NN * HH * 4;
    float*          adst  = (float*)p;          p += (size_t)NN * HH * 4;
    int*            deg   = (int*)p;            p += (size_t)NN * 4;        // zeroed
    int*            cursor= (int*)p;            p += (size_t)NN * 4;
    int*            csr_s = (int*)p;            p += (size_t)TOT * 4;
    int*            rowptr= (int*)p;            p += (size_t)(NN + 1) * 4;

    hipMemsetAsync(deg, 0, (size_t)NN * 4, stream);

    k_prep_x<<<(NN * CC / 8 + 255) / 256, 256, 0, stream>>>(x, xb);
    k_prep_w<<<(HCW * CC + 255) / 256, 256, 0, stream>>>(W, wt);
    k_gemm<<<dim3(NN / 16, HH), 128, 0, stream>>>(xb, wt, xhb);
    k_att<<<(NN * 64 + 255) / 256, 256, 0, stream>>>(xhb, att_s, att_d, asrc, adst);
    k_count<<<(TOT + 255) / 256, 256, 0, stream>>>(ei, deg);
    k_scan<<<1, 1024, 0, stream>>>(deg, rowptr, cursor);
    k_scatter<<<(TOT + 255) / 256, 256, 0, stream>>>(ei, asrc, adst, cursor, csr_s, csr_e);
    {
        const long long threads = (long long)NN * 64;
        const int blocks = (int)((threads + 255) / 256);
        k_gather<<<blocks, 256, 0, stream>>>(rowptr, csr_s, csr_e, (const uint4*)xhb, x, bias, out);
    }
}

// Round 5
// 350.854 us; speedup vs baseline: 3.4822x; 1.2030x over previous
//
#include <hip/hip_runtime.h>
#include <math.h>

#define NN 50000
#define EE 800000
#define TOT (EE + NN)          // 850000 edges incl. self loops
#define CC 128
#define HH 4
#define HCW 512                // H*C

typedef short s16x8 __attribute__((ext_vector_type(8)));
typedef float f32x4 __attribute__((ext_vector_type(4)));

// fp32 -> bf16 bits, round-to-nearest-even
__device__ __forceinline__ unsigned f2bf(float f) {
    unsigned u = __float_as_uint(f);
    return (u + 0x7fffu + ((u >> 16) & 1u)) >> 16;
}
__device__ __forceinline__ float bf_lo(unsigned q) { return __uint_as_float(q << 16); }
__device__ __forceinline__ float bf_hi(unsigned q) { return __uint_as_float(q & 0xffff0000u); }

__device__ __forceinline__ unsigned short f2h_bits(float f) {
    union { _Float16 h; unsigned short u; } cv;
    cv.h = (_Float16)f;
    return cv.u;
}
__device__ __forceinline__ float h2f(unsigned short u) {
    union { _Float16 h; unsigned short u; } cv;
    cv.u = u;
    return (float)cv.h;
}

// -------- P1: x fp32 -> bf16 (8 elems/thread) --------
__global__ __launch_bounds__(256) void k_prep_x(
    const float* __restrict__ x, unsigned short* __restrict__ xb)
{
    const int i = blockIdx.x * 256 + threadIdx.x;
    if (i >= NN * CC / 8) return;
    const float4 v0 = ((const float4*)x)[i * 2];
    const float4 v1 = ((const float4*)x)[i * 2 + 1];
    uint4 o;
    o.x = f2bf(v0.x) | (f2bf(v0.y) << 16);
    o.y = f2bf(v0.z) | (f2bf(v0.w) << 16);
    o.z = f2bf(v1.x) | (f2bf(v1.y) << 16);
    o.w = f2bf(v1.z) | (f2bf(v1.w) << 16);
    ((uint4*)xb)[i] = o;
}

// -------- P2: W [128][512] fp32 -> Wt [512][128] bf16 --------
__global__ __launch_bounds__(256) void k_prep_w(
    const float* __restrict__ W, unsigned short* __restrict__ wt)
{
    const int i = blockIdx.x * 256 + threadIdx.x;   // i = c*128 + k
    if (i >= HCW * CC) return;
    const int c = i >> 7, k = i & 127;
    wt[i] = (unsigned short)f2bf(W[(size_t)k * HCW + c]);
}

// -------- K1: xh = x @ W via MFMA bf16 (swapped operands) + fused att --------
// grid (NN/16, 4 heads), block 128 (2 waves). Wave covers 16 rows x 64 cols.
// mfma(A=wt frag, B=x frag): D row = channel, D col = x-row
__global__ __launch_bounds__(128) void k_gemm(
    const unsigned short* __restrict__ xb,   // [NN][128] bf16
    const unsigned short* __restrict__ wt,   // [512][128] bf16 = W^T
    const float* __restrict__ att_s, const float* __restrict__ att_d,
    unsigned short* __restrict__ xhb,        // [NN][512] bf16
    float* __restrict__ asrc, float* __restrict__ adst)
{
    __shared__ float red[2][2][16];
    const int r0   = blockIdx.x * 16;
    const int h    = blockIdx.y;
    const int wave = threadIdx.x >> 6;
    const int lane = threadIdx.x & 63;
    const int lrow = lane & 15;
    const int kg   = lane >> 4;
    const int n_base = h * 128 + wave * 64;

    f32x4 acc0 = {0.f, 0.f, 0.f, 0.f};
    f32x4 acc1 = {0.f, 0.f, 0.f, 0.f};
    f32x4 acc2 = {0.f, 0.f, 0.f, 0.f};
    f32x4 acc3 = {0.f, 0.f, 0.f, 0.f};

    const unsigned short* bp  = xb + (size_t)(r0 + lrow) * CC + kg * 8;
    const unsigned short* a0p = wt + (size_t)(n_base + 0  + lrow) * CC + kg * 8;
    const unsigned short* a1p = wt + (size_t)(n_base + 16 + lrow) * CC + kg * 8;
    const unsigned short* a2p = wt + (size_t)(n_base + 32 + lrow) * CC + kg * 8;
    const unsigned short* a3p = wt + (size_t)(n_base + 48 + lrow) * CC + kg * 8;

#pragma unroll
    for (int kk = 0; kk < 4; ++kk) {
        const s16x8 b  = *(const s16x8*)(bp  + kk * 32);
        const s16x8 a0 = *(const s16x8*)(a0p + kk * 32);
        const s16x8 a1 = *(const s16x8*)(a1p + kk * 32);
        const s16x8 a2 = *(const s16x8*)(a2p + kk * 32);
        const s16x8 a3 = *(const s16x8*)(a3p + kk * 32);
        acc0 = __builtin_amdgcn_mfma_f32_16x16x32_bf16(a0, b, acc0, 0, 0, 0);
        acc1 = __builtin_amdgcn_mfma_f32_16x16x32_bf16(a1, b, acc1, 0, 0, 0);
        acc2 = __builtin_amdgcn_mfma_f32_16x16x32_bf16(a2, b, acc2, 0, 0, 0);
        acc3 = __builtin_amdgcn_mfma_f32_16x16x32_bf16(a3, b, acc3, 0, 0, 0);
    }

    // lane holds channels n = n_base + ti*16 + kg*4 + r for x-row (r0+lrow)
    unsigned short* orow = xhb + (size_t)(r0 + lrow) * HCW + n_base + kg * 4;
    {
        uint2 o;
        o.x = f2bf(acc0[0]) | (f2bf(acc0[1]) << 16);
        o.y = f2bf(acc0[2]) | (f2bf(acc0[3]) << 16);
        *(uint2*)(orow) = o;
        o.x = f2bf(acc1[0]) | (f2bf(acc1[1]) << 16);
        o.y = f2bf(acc1[2]) | (f2bf(acc1[3]) << 16);
        *(uint2*)(orow + 16) = o;
        o.x = f2bf(acc2[0]) | (f2bf(acc2[1]) << 16);
        o.y = f2bf(acc2[2]) | (f2bf(acc2[3]) << 16);
        *(uint2*)(orow + 32) = o;
        o.x = f2bf(acc3[0]) | (f2bf(acc3[1]) << 16);
        o.y = f2bf(acc3[2]) | (f2bf(acc3[3]) << 16);
        *(uint2*)(orow + 48) = o;
    }

    // fused a_src/a_dst: channel within head = wave*64 + ti*16 + kg*4 + r
    const int cbase = h * CC + wave * 64 + kg * 4;
    float ps, pd;
    {
        const float4 c0 = *(const float4*)(att_s + cbase);
        const float4 c1 = *(const float4*)(att_s + cbase + 16);
        const float4 c2 = *(const float4*)(att_s + cbase + 32);
        const float4 c3 = *(const float4*)(att_s + cbase + 48);
        ps = acc0[0]*c0.x + acc0[1]*c0.y + acc0[2]*c0.z + acc0[3]*c0.w
           + acc1[0]*c1.x + acc1[1]*c1.y + acc1[2]*c1.z + acc1[3]*c1.w
           + acc2[0]*c2.x + acc2[1]*c2.y + acc2[2]*c2.z + acc2[3]*c2.w
           + acc3[0]*c3.x + acc3[1]*c3.y + acc3[2]*c3.z + acc3[3]*c3.w;
    }
    {
        const float4 c0 = *(const float4*)(att_d + cbase);
        const float4 c1 = *(const float4*)(att_d + cbase + 16);
        const float4 c2 = *(const float4*)(att_d + cbase + 32);
        const float4 c3 = *(const float4*)(att_d + cbase + 48);
        pd = acc0[0]*c0.x + acc0[1]*c0.y + acc0[2]*c0.z + acc0[3]*c0.w
           + acc1[0]*c1.x + acc1[1]*c1.y + acc1[2]*c1.z + acc1[3]*c1.w
           + acc2[0]*c2.x + acc2[1]*c2.y + acc2[2]*c2.z + acc2[3]*c2.w
           + acc3[0]*c3.x + acc3[1]*c3.y + acc3[2]*c3.z + acc3[3]*c3.w;
    }
    // reduce over kg (lane bits 4,5)
    ps += __shfl_xor(ps, 16); ps += __shfl_xor(ps, 32);
    pd += __shfl_xor(pd, 16); pd += __shfl_xor(pd, 32);
    red[wave][0][lrow] = ps;
    red[wave][1][lrow] = pd;
    __syncthreads();
    if (threadIdx.x < 16) {
        const int t = threadIdx.x;
        asrc[(r0 + t) * HH + h] = red[0][0][t] + red[1][0][t];
        adst[(r0 + t) * HH + h] = red[0][1][t] + red[1][1][t];
    }
}

// -------- K3: degree count + per-edge position --------
__global__ __launch_bounds__(256) void k_count(
    const int* __restrict__ ei, int* __restrict__ deg, unsigned short* __restrict__ pos)
{
    const int e = blockIdx.x * 256 + threadIdx.x;
    if (e >= TOT) return;
    const int d = (e < EE) ? ei[EE + e] : (e - EE);
    pos[e] = (unsigned short)atomicAdd(deg + d, 1);
}

// -------- K4: exclusive scan of deg -> rowptr (single block) --------
__global__ __launch_bounds__(1024) void k_scan(
    const int* __restrict__ deg, int* __restrict__ rowptr)
{
    __shared__ int sm[1024];
    const int t = threadIdx.x;
    const int CH = (NN + 1023) / 1024;   // 49
    const int base = t * CH;
    int sum = 0;
    for (int i = 0; i < CH; ++i) {
        int idx = base + i;
        if (idx < NN) sum += deg[idx];
    }
    sm[t] = sum;
    __syncthreads();
    for (int off = 1; off < 1024; off <<= 1) {
        int v = (t >= off) ? sm[t - off] : 0;
        __syncthreads();
        sm[t] += v;
        __syncthreads();
    }
    int run = (t > 0) ? sm[t - 1] : 0;
    for (int i = 0; i < CH; ++i) {
        int idx = base + i;
        if (idx < NN) {
            rowptr[idx] = run;
            run += deg[idx];
        }
    }
    if (t == 0) rowptr[NN] = TOT;
}

// -------- K5: atomic-free scatter into dst-sorted CSR, 16B records --------
__global__ __launch_bounds__(256) void k_scatter(
    const int* __restrict__ ei, const float* __restrict__ asrc,
    const float* __restrict__ adst, const int* __restrict__ rowptr,
    const unsigned short* __restrict__ pos, uint4* __restrict__ csr)
{
    const int e = blockIdx.x * 256 + threadIdx.x;
    if (e >= TOT) return;
    int s, d;
    if (e < EE) { s = ei[e]; d = ei[EE + e]; } else { s = d = e - EE; }
    const float4 a = *(const float4*)(asrc + (size_t)s * HH);
    const float4 b = *(const float4*)(adst + (size_t)d * HH);
    float4 v;
    v.x = a.x + b.x; v.x = v.x > 0.f ? v.x : 0.2f * v.x;
    v.y = a.y + b.y; v.y = v.y > 0.f ? v.y : 0.2f * v.y;
    v.z = a.z + b.z; v.z = v.z > 0.f ? v.z : 0.2f * v.z;
    v.w = a.w + b.w; v.w = v.w > 0.f ? v.w : 0.2f * v.w;
    uint4 rec;
    rec.x = (unsigned)s;
    rec.y = (unsigned)f2h_bits(v.x) | ((unsigned)f2h_bits(v.y) << 16);
    rec.z = (unsigned)f2h_bits(v.z) | ((unsigned)f2h_bits(v.w) << 16);
    rec.w = 0;
    csr[rowptr[d] + pos[e]] = rec;
}

// -------- K6: fused softmax + gather + residual; head-major lanes --------
// lane = h*16 + t: owns channels h*128 + t*8 .. +7 (uint4 index `lane` in xh row)
__global__ __launch_bounds__(256) void k_gather(
    const int* __restrict__ rowptr, const uint4* __restrict__ csr,
    const uint4* __restrict__ xhb4, const float* __restrict__ x,
    const float* __restrict__ bias, float* __restrict__ out)
{
    const int gtid = blockIdx.x * 256 + threadIdx.x;
    const int n    = gtid >> 6;
    const int lane = threadIdx.x & 63;
    if (n >= NN) return;
    const int h = lane >> 4;
    const int t = lane & 15;

    const int beg = rowptr[n];
    const int end = rowptr[n + 1];

    // phase 1: online softmax for head h; the 16 lanes of the head stride by 16
    float m = -1e30f, ssum = 0.f;
    for (int j = beg + t; j < end; j += 16) {
        const uint4 rec = csr[j];
        const unsigned wsel = (h & 2) ? rec.z : rec.y;
        const unsigned short us = (h & 1) ? (unsigned short)(wsel >> 16)
                                          : (unsigned short)(wsel & 0xffffu);
        const float e = h2f(us);
        const float nm = fmaxf(m, e);
        ssum = ssum * __expf(m - nm) + __expf(e - nm);
        m = nm;
    }
#pragma unroll
    for (int off = 1; off < 16; off <<= 1) {
        const float om = __shfl_xor(m, off);
        const float os = __shfl_xor(ssum, off);
        const float nm = fmaxf(m, om);
        ssum = ssum * __expf(m - nm) + os * __expf(om - nm);
        m = nm;
    }
    const float inv = 0.25f / (ssum + 1e-16f);

    // phase 2: weighted gather, 2-way unrolled for MLP
    float r0 = 0.f, r1 = 0.f, r2 = 0.f, r3 = 0.f;
    float r4 = 0.f, r5 = 0.f, r6 = 0.f, r7 = 0.f;
    int j = beg;
    for (; j + 1 < end; j += 2) {
        const uint4 eA = csr[j];
        const uint4 eB = csr[j + 1];
        const unsigned wA = (h & 2) ? eA.z : eA.y;
        const unsigned wB = (h & 2) ? eB.z : eB.y;
        const unsigned short uA = (h & 1) ? (unsigned short)(wA >> 16)
                                          : (unsigned short)(wA & 0xffffu);
        const unsigned short uB = (h & 1) ? (unsigned short)(wB >> 16)
                                          : (unsigned short)(wB & 0xffffu);
        const float wgA = __expf(h2f(uA) - m);
        const float wgB = __expf(h2f(uB) - m);
        const uint4 qA = xhb4[(size_t)eA.x * 64 + lane];
        const uint4 qB = xhb4[(size_t)eB.x * 64 + lane];
        r0 += wgA * bf_lo(qA.x) + wgB * bf_lo(qB.x);
        r1 += wgA * bf_hi(qA.x) + wgB * bf_hi(qB.x);
        r2 += wgA * bf_lo(qA.y) + wgB * bf_lo(qB.y);
        r3 += wgA * bf_hi(qA.y) + wgB * bf_hi(qB.y);
        r4 += wgA * bf_lo(qA.z) + wgB * bf_lo(qB.z);
        r5 += wgA * bf_hi(qA.z) + wgB * bf_hi(qB.z);
        r6 += wgA * bf_lo(qA.w) + wgB * bf_lo(qB.w);
        r7 += wgA * bf_hi(qA.w) + wgB * bf_hi(qB.w);
    }
    if (j < end) {
        const uint4 eA = csr[j];
        const unsigned wA = (h & 2) ? eA.z : eA.y;
        const unsigned short uA = (h & 1) ? (unsigned short)(wA >> 16)
                                          : (unsigned short)(wA & 0xffffu);
        const float wgA = __expf(h2f(uA) - m);
        const uint4 qA = xhb4[(size_t)eA.x * 64 + lane];
        r0 += wgA * bf_lo(qA.x); r1 += wgA * bf_hi(qA.x);
        r2 += wgA * bf_lo(qA.y); r3 += wgA * bf_hi(qA.y);
        r4 += wgA * bf_lo(qA.z); r5 += wgA * bf_hi(qA.z);
        r6 += wgA * bf_lo(qA.w); r7 += wgA * bf_hi(qA.w);
    }
    r0 *= inv; r1 *= inv; r2 *= inv; r3 *= inv;
    r4 *= inv; r5 *= inv; r6 *= inv; r7 *= inv;

    // sum across the 4 head groups (lane bits 4..5)
#pragma unroll
    for (int off = 16; off < 64; off <<= 1) {
        r0 += __shfl_xor(r0, off); r1 += __shfl_xor(r1, off);
        r2 += __shfl_xor(r2, off); r3 += __shfl_xor(r3, off);
        r4 += __shfl_xor(r4, off); r5 += __shfl_xor(r5, off);
        r6 += __shfl_xor(r6, off); r7 += __shfl_xor(r7, off);
    }

    if (h == 0) {
        const int c = t * 8;
        const float4 x0 = *(const float4*)(x + (size_t)n * CC + c);
        const float4 x1 = *(const float4*)(x + (size_t)n * CC + c + 4);
        const float4 b0 = *(const float4*)(bias + c);
        const float4 b1 = *(const float4*)(bias + c + 4);
        float4 o0, o1;
        o0.x = 0.8f * x0.x + 0.2f * (r0 + b0.x);
        o0.y = 0.8f * x0.y + 0.2f * (r1 + b0.y);
        o0.z = 0.8f * x0.z + 0.2f * (r2 + b0.z);
        o0.w = 0.8f * x0.w + 0.2f * (r3 + b0.w);
        o1.x = 0.8f * x1.x + 0.2f * (r4 + b1.x);
        o1.y = 0.8f * x1.y + 0.2f * (r5 + b1.y);
        o1.z = 0.8f * x1.z + 0.2f * (r6 + b1.z);
        o1.w = 0.8f * x1.w + 0.2f * (r7 + b1.w);
        *(float4*)(out + (size_t)n * CC + c)     = o0;
        *(float4*)(out + (size_t)n * CC + c + 4) = o1;
    }
}

extern "C" void kernel_launch(void* const* d_in, const int* in_sizes, int n_in,
                              void* d_out, int out_size, void* d_ws, size_t ws_size,
                              hipStream_t stream)
{
    const float* x     = (const float*)d_in[0];
    const int*   ei    = (const int*)d_in[1];
    const float* W     = (const float*)d_in[2];
    const float* att_s = (const float*)d_in[3];
    const float* att_d = (const float*)d_in[4];
    const float* bias  = (const float*)d_in[5];
    float* out = (float*)d_out;

    char* p = (char*)d_ws;
    unsigned short* xhb   = (unsigned short*)p; p += (size_t)NN * HCW * 2;  // 51.2 MB
    unsigned short* xb    = (unsigned short*)p; p += (size_t)NN * CC * 2;   // 12.8 MB
    unsigned short* wt    = (unsigned short*)p; p += (size_t)HCW * CC * 2;  // 128 KB
    uint4*          csr   = (uint4*)p;          p += (size_t)TOT * 16;      // 13.6 MB
    float*          asrc  = (float*)p;          p += (size_t)NN * HH * 4;
    float*          adst  = (float*)p;          p += (size_t)NN * HH * 4;
    int*            deg   = (int*)p;            p += (size_t)NN * 4;        // zeroed
    unsigned short* pos   = (unsigned short*)p; p += (size_t)TOT * 2;
    int*            rowptr= (int*)p;            p += (size_t)(NN + 1) * 4;

    hipMemsetAsync(deg, 0, (size_t)NN * 4, stream);

    k_prep_x<<<(NN * CC / 8 + 255) / 256, 256, 0, stream>>>(x, xb);
    k_prep_w<<<(HCW * CC + 255) / 256, 256, 0, stream>>>(W, wt);
    k_gemm<<<dim3(NN / 16, HH), 128, 0, stream>>>(xb, wt, att_s, att_d, xhb, asrc, adst);
    k_count<<<(TOT + 255) / 256, 256, 0, stream>>>(ei, deg, pos);
    k_scan<<<1, 1024, 0, stream>>>(deg, rowptr);
    k_scatter<<<(TOT + 255) / 256, 256, 0, stream>>>(ei, asrc, adst, rowptr, pos, csr);
    {
        const long long threads = (long long)NN * 64;
        const int blocks = (int)((threads + 255) / 256);
        k_gather<<<blocks, 256, 0, stream>>>(rowptr, csr, (const uint4*)xhb, x, bias, out);
    }
}